// Round 3
// baseline (113.431 us; speedup 1.0000x reference)
//
#include <hip/hip_runtime.h>

// FHE BSGS: out[b,s] = sum_{t=0..15} x[b,(s+2^t)&0xFFFF] * diag[t,s], rolled by 32768.
// Roll by S/2 on the 2^16 ring == store to column s ^ 0x8000 (coalesced).
//
// v3: v2 was latency-bound (2 blocks/CU, serialized stage->compute chain; 165 MB
// at only 1.9 TB/s). Changes:
//   - NB 8 -> 4: grid 512 -> 1024 blocks (4 blocks/CU, 16 waves/CU).
//   - register prefetch pipeline: batch b+1's x loads issue right after batch b's
//     LDS writes and fly during compute+store (~full iteration window).
//   - __launch_bounds__(256,4) to hold VGPR <= 128 (4 waves/SIMD).
// Traffic: diag 67 MB + x staging 114.7 MB + out 16.8 MB ~= 198 MB -> ~33 us at 6 TB/s.

#define SLOTS 65536
#define MASK  65535
#define CTILE 1024
#define NB    4
#define XFOOT 7168   // 3072 (merged shifts 1..2048) + 4*1024 (shifts 4096..32768)

__global__ __launch_bounds__(256, 4) void bsgs_kernel(
    const float* __restrict__ x,
    const float* __restrict__ diag,
    float* __restrict__ out)
{
    __shared__ float ldsx[XFOOT];
    const int tid = threadIdx.x;
    const int c   = blockIdx.x * CTILE;      // column tile base
    const int bg  = blockIdx.y * NB;         // first batch for this block
    const int jj  = tid * 4;                 // thread's column offset in tile

    // Global x offsets (per batch-row) and LDS offsets for this thread's 7 staged float4s.
    int goff[7], loff[7];
#pragma unroll
    for (int k = 0; k < 3; ++k) {            // seg0: x[c .. c+3072)
        loff[k] = (tid + k * 256) * 4;
        goff[k] = (c + loff[k]) & MASK;
    }
#pragma unroll
    for (int s = 0; s < 4; ++s) {            // segs for shifts 4096<<s
        loff[3 + s] = 3072 + s * 1024 + jj;
        goff[3 + s] = (c + (4096 << s) + jj) & MASK;
    }

    // diag[t, c+jj .. +3], t=0..15 -- 64 VGPRs, reused across NB batches.
    float4 dreg[16];
#pragma unroll
    for (int t = 0; t < 16; ++t)
        dreg[t] = *(const float4*)(diag + t * SLOTS + c + jj);

    // Prologue: prefetch batch bg's x footprint into registers.
    float4 pf[7];
    {
        const float* __restrict__ xb = x + (size_t)bg * SLOTS;
#pragma unroll
        for (int k = 0; k < 7; ++k) pf[k] = *(const float4*)(xb + goff[k]);
    }

    for (int b = 0; b < NB; ++b) {
        // Drain prefetch into LDS (compiler inserts the vmcnt wait here; loads
        // have been in flight for a full iteration by now).
#pragma unroll
        for (int k = 0; k < 7; ++k) *(float4*)(ldsx + loff[k]) = pf[k];
        __syncthreads();

        // Issue next batch's prefetch immediately -- hides its latency behind compute.
        if (b + 1 < NB) {
            const float* __restrict__ xn = x + (size_t)(bg + b + 1) * SLOTS;
#pragma unroll
            for (int k = 0; k < 7; ++k) pf[k] = *(const float4*)(xn + goff[k]);
        }

        float4 acc = make_float4(0.f, 0.f, 0.f, 0.f);
        const float4 vA = *(const float4*)(ldsx + jj);       // x[c+jj .. +3]
        const float4 vB = *(const float4*)(ldsx + jj + 4);   // x[c+jj+4 .. +7]

        // t=0, shift 1
        acc.x += vA.y*dreg[0].x; acc.y += vA.z*dreg[0].y; acc.z += vA.w*dreg[0].z; acc.w += vB.x*dreg[0].w;
        // t=1, shift 2
        acc.x += vA.z*dreg[1].x; acc.y += vA.w*dreg[1].y; acc.z += vB.x*dreg[1].z; acc.w += vB.y*dreg[1].w;
        // t=2, shift 4
        acc.x += vB.x*dreg[2].x; acc.y += vB.y*dreg[2].y; acc.z += vB.z*dreg[2].z; acc.w += vB.w*dreg[2].w;
        // t=3..11, shifts 8..2048 inside seg0 (max idx 1020+2048+3 = 3071)
#pragma unroll
        for (int t = 3; t <= 11; ++t) {
            const float4 v = *(const float4*)(ldsx + jj + (1 << t));
            acc.x += v.x*dreg[t].x; acc.y += v.y*dreg[t].y; acc.z += v.z*dreg[t].z; acc.w += v.w*dreg[t].w;
        }
        // t=12..15, shifts 4096/8192/16384/32768: dedicated segments
#pragma unroll
        for (int s = 0; s < 4; ++s) {
            const int t = 12 + s;
            const float4 v = *(const float4*)(ldsx + 3072 + s * 1024 + jj);
            acc.x += v.x*dreg[t].x; acc.y += v.y*dreg[t].y; acc.z += v.z*dreg[t].z; acc.w += v.w*dreg[t].w;
        }

        // roll by 32768 == XOR top column bit; store coalesced
        *(float4*)(out + (size_t)(bg + b) * SLOTS + ((c + jj) ^ 32768)) = acc;

        __syncthreads();   // readers done before next iteration overwrites LDS
    }
}

extern "C" void kernel_launch(void* const* d_in, const int* in_sizes, int n_in,
                              void* d_out, int out_size, void* d_ws, size_t ws_size,
                              hipStream_t stream) {
    const float* x    = (const float*)d_in[0];   // (64, 65536) fp32
    const float* diag = (const float*)d_in[1];   // (16, 65536) fp32
    float* out        = (float*)d_out;           // (64, 65536) fp32
    // d_in[2] = stride (1), d_in[3] = reps (1) -- compile-time constants here.

    dim3 grid(SLOTS / CTILE, 64 / NB);           // 64 tiles x 16 batch groups = 1024 blocks
    bsgs_kernel<<<grid, dim3(256), 0, stream>>>(x, diag, out);
}

// Round 4
// 86.376 us; speedup vs baseline: 1.3132x; 1.3132x over previous
//
#include <hip/hip_runtime.h>

// FHE BSGS: out[b,s] = sum_{t=0..15} x[b,(s+2^t)&0xFFFF] * diag[t,s], rolled by 32768.
// Roll by S/2 on the 2^16 ring == store to column s ^ 0x8000 (coalesced).
//
// v4: the LDS/barrier pipeline (v2/v3) is latency-bound, not BW-bound (v3: 3.7 TB/s,
// VALUBusy 2.3%, VGPR 48 proves launch_bounds(,4) evicted the diag registers).
// Back to v1's barrier-free streaming shape, which served 554 MB at ~14 TB/s, but
// with request-traffic cut from 554 -> ~336 MB:
//   - NB=4 batch rows per thread: diag float4 reused 4x from registers (277->69 MB)
//   - sliding-window aligned loads for shifts 1/2/4 (15 x-loads per col-quad)
//   - XCD swizzle: batch-group = bid&15, so dispatch round-robin (bid%8) clusters
//     batch-groups {y, y+8} on one XCD -> 2 MB x footprint fits the 4 MB per-XCD L2.
// No launch_bounds min-waves cap: acc[4]+pipeline needs ~80-100 VGPRs resident.

#define SLOTS 65536
#define MASK  65535
#define NB    4

__global__ __launch_bounds__(256) void bsgs_kernel(
    const float* __restrict__ x,
    const float* __restrict__ diag,
    float* __restrict__ out)
{
    const int bid  = blockIdx.x;          // 0..1023
    const int y    = bid & 15;            // batch-group; XCD = bid%8 = y%8 (heuristic)
    const int xidx = bid >> 4;            // column block 0..63
    const int j    = xidx * 1024 + threadIdx.x * 4;   // column base (multiple of 4)
    const int bg   = y * NB;

    const float* __restrict__ xb = x + (size_t)bg * SLOTS;

    float4 acc[NB];
#pragma unroll
    for (int b = 0; b < NB; ++b) acc[b] = make_float4(0.f, 0.f, 0.f, 0.f);

    // t = 0,1,2 (shifts 1,2,4) via sliding window: vA = x[j..j+3], vB = x[j+4..j+7]
    {
        const float4 d0 = *(const float4*)(diag + 0 * SLOTS + j);
        const float4 d1 = *(const float4*)(diag + 1 * SLOTS + j);
        const float4 d2 = *(const float4*)(diag + 2 * SLOTS + j);
#pragma unroll
        for (int b = 0; b < NB; ++b) {
            const float* xr = xb + (size_t)b * SLOTS;
            const float4 vA = *(const float4*)(xr + j);
            const float4 vB = *(const float4*)(xr + ((j + 4) & MASK));
            acc[b].x += vA.y * d0.x + vA.z * d1.x + vB.x * d2.x;
            acc[b].y += vA.z * d0.y + vA.w * d1.y + vB.y * d2.y;
            acc[b].z += vA.w * d0.z + vB.x * d1.z + vB.z * d2.z;
            acc[b].w += vB.x * d0.w + vB.y * d1.w + vB.w * d2.w;
        }
    }

    // t = 3..15 (shifts 8..32768): aligned float4 x-loads, diag reused across NB rows
#pragma unroll
    for (int t = 3; t < 16; ++t) {
        const float4 d = *(const float4*)(diag + t * SLOTS + j);
        const int o = (j + (1 << t)) & MASK;
#pragma unroll
        for (int b = 0; b < NB; ++b) {
            const float4 v = *(const float4*)(xb + (size_t)b * SLOTS + o);
            acc[b].x += v.x * d.x; acc[b].y += v.y * d.y;
            acc[b].z += v.z * d.z; acc[b].w += v.w * d.w;
        }
    }

    // roll by 32768 == XOR top column bit; stores stay coalesced
#pragma unroll
    for (int b = 0; b < NB; ++b)
        *(float4*)(out + (size_t)(bg + b) * SLOTS + (j ^ 32768)) = acc[b];
}

extern "C" void kernel_launch(void* const* d_in, const int* in_sizes, int n_in,
                              void* d_out, int out_size, void* d_ws, size_t ws_size,
                              hipStream_t stream) {
    const float* x    = (const float*)d_in[0];   // (64, 65536) fp32
    const float* diag = (const float*)d_in[1];   // (16, 65536) fp32
    float* out        = (float*)d_out;           // (64, 65536) fp32
    // d_in[2] = stride (1), d_in[3] = reps (1) -- compile-time constants here.

    bsgs_kernel<<<dim3(1024), dim3(256), 0, stream>>>(x, diag, out);
}